// Round 3
// baseline (638.372 us; speedup 1.0000x reference)
//
#include <hip/hip_runtime.h>
#include <math.h>

// Problem constants (from reference)
#define N_ENT 100000
#define N_REL 237
#define DIM   128
#define NE    400000
#define CHUNK 32    // edges per wave in k_relseg

// ---------------------------------------------------------------------------
// Pipeline:
//  1. Per-node projections: Ps = ent@Wa[:,0:128]^T, Pd = ent@Wa[:,256:384]^T,
//     Pr = rel@Wa[:,128:256]^T + ba  (6x fewer FLOPs than per-edge GEMM).
//  2. Build src-CSR AND rel-CSR on device (one histogram pass, scans, one scatter).
//  3. k_seg: one wave per src entity, register-accumulate sum(eb*c), sum(eb),
//     finalize h_ent = ELU(acc/ebs) in-kernel. NO global atomics at all.
//  4. k_relseg: one wave per 32-edge run in rel-CSR order; recomputes eb*c
//     (Pr held in registers per segment), register-accumulates, flushes one
//     512B atomic per rel boundary (~6 MB total vs 205 MB write-through before).
//  5. k_rel_final: divide by count + ELU.
// ---------------------------------------------------------------------------

__global__ void k_transpose_wa(const float* __restrict__ Wa, float* __restrict__ WaT) {
    int i = blockIdx.x * 256 + threadIdx.x;
    if (i < 384 * 128) {
        int k = i >> 7, j = i & 127;
        WaT[i] = Wa[j * 384 + k];   // WaT[k][j] = Wa[j][k]
    }
}

__global__ void k_proj_rel(const float* __restrict__ rel_e, const float* __restrict__ Wa,
                           const float* __restrict__ ba, float* __restrict__ Pr) {
    int i = blockIdx.x * 256 + threadIdx.x;
    if (i >= N_REL * DIM) return;
    int r = i >> 7, j = i & 127;
    float acc = ba[j];
    const float* wrow = Wa + j * 384 + 128;   // middle segment
    const float* erow = rel_e + r * DIM;
    #pragma unroll 8
    for (int k = 0; k < DIM; ++k) acc += erow[k] * wrow[k];
    Pr[i] = acc;
}

// Fused P_s / P_d projection (fp32 vector FMA; no fp32 MFMA on CDNA4).
// Wa k-slices staged in LDS to kill the 16x L1/L2 re-read across row-groups.
#define KC 16
__global__ __launch_bounds__(256) void k_proj_ent(const float* __restrict__ ent,
        const float* __restrict__ WaT, float* __restrict__ Ps, float* __restrict__ Pd) {
    __shared__ float tile[64 * 132];          // 33.8 KB
    __shared__ float wsh[2 * KC * 128];       // 16 KB: [0..KC*128)=s slice, rest=d slice
    const int tid = threadIdx.x;
    const int row0 = blockIdx.x * 64;

    for (int i = tid; i < 64 * 32; i += 256) {
        int r = i >> 5, c4 = i & 31;
        float4 v = make_float4(0.f, 0.f, 0.f, 0.f);
        if (row0 + r < N_ENT) v = *(const float4*)(ent + (size_t)(row0 + r) * DIM + c4 * 4);
        *(float4*)(tile + r * 132 + c4 * 4) = v;
    }

    const int rg = tid >> 4, cg = tid & 15;
    const int r0 = rg * 4, j0 = cg * 8;

    float accs[4][8], accd[4][8];
    #pragma unroll
    for (int i = 0; i < 4; ++i)
        #pragma unroll
        for (int j = 0; j < 8; ++j) { accs[i][j] = 0.f; accd[i][j] = 0.f; }

    for (int kc = 0; kc < DIM; kc += KC) {
        __syncthreads();   // first iter: tile ready; later: protect wsh readers
        for (int i = tid; i < KC * 32; i += 256) {   // KC*32 float4 per matrix
            int kk = i >> 5, c4 = i & 31;
            *(float4*)(wsh + kk * 128 + c4 * 4) =
                *(const float4*)(WaT + (kc + kk) * 128 + c4 * 4);
            *(float4*)(wsh + KC * 128 + kk * 128 + c4 * 4) =
                *(const float4*)(WaT + (256 + kc + kk) * 128 + c4 * 4);
        }
        __syncthreads();
        #pragma unroll
        for (int kk = 0; kk < KC; ++kk) {
            float4 a0 = *(float4*)(wsh + kk * 128 + j0);
            float4 a1 = *(float4*)(wsh + kk * 128 + j0 + 4);
            float4 b0 = *(float4*)(wsh + KC * 128 + kk * 128 + j0);
            float4 b1 = *(float4*)(wsh + KC * 128 + kk * 128 + j0 + 4);
            float ws[8] = {a0.x, a0.y, a0.z, a0.w, a1.x, a1.y, a1.z, a1.w};
            float wd[8] = {b0.x, b0.y, b0.z, b0.w, b1.x, b1.y, b1.z, b1.w};
            #pragma unroll
            for (int i = 0; i < 4; ++i) {
                float e = tile[(r0 + i) * 132 + kc + kk];
                #pragma unroll
                for (int j = 0; j < 8; ++j) {
                    accs[i][j] += e * ws[j];
                    accd[i][j] += e * wd[j];
                }
            }
        }
    }

    #pragma unroll
    for (int i = 0; i < 4; ++i) {
        int row = row0 + r0 + i;
        if (row < N_ENT) {
            float4 o;
            o = make_float4(accs[i][0], accs[i][1], accs[i][2], accs[i][3]);
            *(float4*)(Ps + (size_t)row * DIM + j0) = o;
            o = make_float4(accs[i][4], accs[i][5], accs[i][6], accs[i][7]);
            *(float4*)(Ps + (size_t)row * DIM + j0 + 4) = o;
            o = make_float4(accd[i][0], accd[i][1], accd[i][2], accd[i][3]);
            *(float4*)(Pd + (size_t)row * DIM + j0) = o;
            o = make_float4(accd[i][4], accd[i][5], accd[i][6], accd[i][7]);
            *(float4*)(Pd + (size_t)row * DIM + j0 + 4) = o;
        }
    }
}

// ---------------- CSR build ----------------
// One pass: src histogram (global atomics on 400KB, L2) + rel histogram (LDS).
__global__ void k_hist2(const int* __restrict__ trip, int* __restrict__ scnt,
                        int* __restrict__ rcnt) {
    __shared__ int lh[N_REL];
    for (int i = threadIdx.x; i < N_REL; i += 256) lh[i] = 0;
    __syncthreads();
    int e = blockIdx.x * 256 + threadIdx.x;
    if (e < NE) {
        atomicAdd(scnt + trip[3 * e], 1);
        atomicAdd(&lh[trip[3 * e + 2]], 1);
    }
    __syncthreads();
    for (int i = threadIdx.x; i < N_REL; i += 256)
        if (lh[i]) atomicAdd(rcnt + i, lh[i]);
}

// 98 blocks x 256 thr; each thread owns 4 consecutive entries.
__global__ void k_scan1(const int* __restrict__ cnt, int* __restrict__ escan,
                        int* __restrict__ bsum) {
    __shared__ int sh[256];
    const int t = threadIdx.x;
    int base = blockIdx.x * 1024 + t * 4;
    int v[4]; int s = 0;
    #pragma unroll
    for (int k = 0; k < 4; ++k) { int idx = base + k; v[k] = (idx < N_ENT) ? cnt[idx] : 0; s += v[k]; }
    sh[t] = s; __syncthreads();
    for (int off = 1; off < 256; off <<= 1) {
        int u = (t >= off) ? sh[t - off] : 0;
        __syncthreads();
        sh[t] += u;
        __syncthreads();
    }
    int run = sh[t] - s;
    #pragma unroll
    for (int k = 0; k < 4; ++k) { int idx = base + k; if (idx < N_ENT) escan[idx] = run; run += v[k]; }
    if (t == 255) bsum[blockIdx.x] = sh[255];
}

__global__ void k_scan2(int* __restrict__ bsum) {   // 1 block, exclusive over 98
    __shared__ int sh[128];
    const int t = threadIdx.x;
    int v = (t < 98) ? bsum[t] : 0;
    sh[t] = v; __syncthreads();
    for (int off = 1; off < 128; off <<= 1) {
        int u = (t >= off) ? sh[t - off] : 0;
        __syncthreads();
        sh[t] += u;
        __syncthreads();
    }
    if (t < 98) bsum[t] = sh[t] - v;
}

__global__ void k_scan3(int* __restrict__ row_start, const int* __restrict__ bsum,
                        int* __restrict__ cursor) {
    int i = blockIdx.x * 256 + threadIdx.x;
    if (i < N_ENT) {
        int v = row_start[i] + bsum[i >> 10];
        row_start[i] = v;
        cursor[i] = v;
    } else if (i == N_ENT) {
        row_start[N_ENT] = NE;
    }
}

// single block: exclusive scan of rcnt[237] -> rrow, init rcursor; rrow[237]=NE
__global__ void k_relscan(const int* __restrict__ rcnt, int* __restrict__ rrow,
                          int* __restrict__ rcursor) {
    __shared__ int sh[256];
    const int t = threadIdx.x;
    int v = (t < N_REL) ? rcnt[t] : 0;
    sh[t] = v; __syncthreads();
    for (int off = 1; off < 256; off <<= 1) {
        int u = (t >= off) ? sh[t - off] : 0;
        __syncthreads();
        sh[t] += u;
        __syncthreads();
    }
    int excl = sh[t] - v;
    if (t <= N_REL) rrow[t] = excl;        // t==N_REL gets total == NE
    if (t < N_REL) rcursor[t] = excl;
}

// one pass builds both CSRs
__global__ void k_scatter2(const int* __restrict__ trip, int* __restrict__ scursor,
                           int* __restrict__ rcursor, int* __restrict__ sdst,
                           int* __restrict__ srel, int* __restrict__ rsrc,
                           int* __restrict__ rdst) {
    int e = blockIdx.x * 256 + threadIdx.x;
    if (e >= NE) return;
    int s = trip[3 * e], d = trip[3 * e + 1], r = trip[3 * e + 2];
    int p1 = atomicAdd(scursor + s, 1);
    sdst[p1] = d;
    srel[p1] = r;
    int p2 = atomicAdd(rcursor + r, 1);
    rsrc[p2] = s;
    rdst[p2] = d;
}

// ---------------- main segment kernels ----------------
// One wave per src entity; zero global atomics.
__global__ __launch_bounds__(256) void k_seg(const int* __restrict__ row_start,
        const int* __restrict__ sdst, const int* __restrict__ srel,
        const float* __restrict__ Ps, const float* __restrict__ Pd, const float* __restrict__ Pr,
        const float* __restrict__ Wa2, const float* __restrict__ ba2,
        float* __restrict__ out) {
    const int lane = threadIdx.x & 63;
    const int s = (blockIdx.x * 256 + threadIdx.x) >> 6;
    if (s >= N_ENT) return;
    const float w0 = Wa2[lane], w1 = Wa2[64 + lane];
    const float bb = ba2[0];

    const int beg = row_start[s], end = row_start[s + 1];
    const float ps0 = Ps[(size_t)s * DIM + lane];
    const float ps1 = Ps[(size_t)s * DIM + 64 + lane];

    float acc0 = 0.f, acc1 = 0.f, ebs = 0.f;
    for (int j = beg; j < end; ++j) {
        int d = sdst[j];
        int r = srel[j];
        float c0 = ps0 + Pr[r * DIM + lane]      + Pd[(size_t)d * DIM + lane];
        float c1 = ps1 + Pr[r * DIM + 64 + lane] + Pd[(size_t)d * DIM + 64 + lane];
        float p = c0 * w0 + c1 * w1;
        #pragma unroll
        for (int off = 32; off > 0; off >>= 1) p += __shfl_xor(p, off, 64);
        float b = p + bb;
        b = (b > 0.f) ? b : 0.01f * b;        // leaky_relu slope 0.01
        float eb = expf(b);
        acc0 += eb * c0; acc1 += eb * c1; ebs += eb;
    }

    float ebsv = (ebs == 0.f) ? 1e-12f : ebs;
    float h0 = acc0 / ebsv, h1 = acc1 / ebsv;
    out[(size_t)s * DIM + lane]      = (h0 > 0.f) ? h0 : expm1f(h0);  // elu
    out[(size_t)s * DIM + 64 + lane] = (h1 > 0.f) ? h1 : expm1f(h1);
}

// One wave per CHUNK-edge run in rel-CSR order; flush per rel boundary.
__global__ __launch_bounds__(256) void k_relseg(const int* __restrict__ rrow,
        const int* __restrict__ rsrc, const int* __restrict__ rdst,
        const float* __restrict__ Ps, const float* __restrict__ Pd, const float* __restrict__ Pr,
        const float* __restrict__ Wa2, const float* __restrict__ ba2,
        float* __restrict__ relp) {
    const int lane = threadIdx.x & 63;
    const int w = (blockIdx.x * 256 + threadIdx.x) >> 6;
    const int j0 = w * CHUNK;
    if (j0 >= NE) return;
    const int jend = (j0 + CHUNK < NE) ? j0 + CHUNK : NE;
    const float w0 = Wa2[lane], w1 = Wa2[64 + lane];
    const float bb = ba2[0];

    // binary search: cur = max r with rrow[r] <= j0
    int lo = 0, hi = N_REL - 1;
    while (lo < hi) { int mid = (lo + hi + 1) >> 1; if (rrow[mid] <= j0) lo = mid; else hi = mid - 1; }
    int cur = lo;
    int nxt = rrow[cur + 1];
    float pr0 = Pr[cur * DIM + lane], pr1 = Pr[cur * DIM + 64 + lane];

    float a0 = 0.f, a1 = 0.f;
    bool have = false;
    for (int j = j0; j < jend; ++j) {
        while (j >= nxt) {
            if (have) {
                atomicAdd(relp + cur * DIM + lane,      a0);
                atomicAdd(relp + cur * DIM + 64 + lane, a1);
                a0 = a1 = 0.f; have = false;
            }
            ++cur;
            nxt = rrow[cur + 1];
            pr0 = Pr[cur * DIM + lane]; pr1 = Pr[cur * DIM + 64 + lane];
        }
        int s = rsrc[j], d = rdst[j];
        float c0 = pr0 + Ps[(size_t)s * DIM + lane]      + Pd[(size_t)d * DIM + lane];
        float c1 = pr1 + Ps[(size_t)s * DIM + 64 + lane] + Pd[(size_t)d * DIM + 64 + lane];
        float p = c0 * w0 + c1 * w1;
        #pragma unroll
        for (int off = 32; off > 0; off >>= 1) p += __shfl_xor(p, off, 64);
        float b = p + bb;
        b = (b > 0.f) ? b : 0.01f * b;
        float eb = expf(b);
        a0 += eb * c0; a1 += eb * c1; have = true;
    }
    if (have) {
        atomicAdd(relp + cur * DIM + lane,      a0);
        atomicAdd(relp + cur * DIM + 64 + lane, a1);
    }
}

__global__ void k_rel_final(float* __restrict__ out, const float* __restrict__ relp,
                            const int* __restrict__ rcnt) {
    int i = blockIdx.x * 256 + threadIdx.x;
    if (i >= N_REL * DIM) return;
    int r = i >> 7;
    float h = relp[i] / fmaxf((float)rcnt[r], 1.0f);
    out[N_ENT * DIM + i] = (h > 0.f) ? h : expm1f(h);
}

extern "C" void kernel_launch(void* const* d_in, const int* in_sizes, int n_in,
                              void* d_out, int out_size, void* d_ws, size_t ws_size,
                              hipStream_t stream) {
    const int*   trip = (const int*)d_in[0];
    const float* ent  = (const float*)d_in[1];
    const float* rele = (const float*)d_in[2];
    const float* Wa   = (const float*)d_in[3];
    const float* ba   = (const float*)d_in[4];
    const float* Wa2  = (const float*)d_in[5];
    const float* ba2  = (const float*)d_in[6];
    float* out = (float*)d_out;

    float* ws   = (float*)d_ws;
    float* WaT  = ws;                                   // 384*128
    float* Ps   = WaT + 384 * 128;                      // N_ENT*128
    float* Pd   = Ps + (size_t)N_ENT * DIM;             // N_ENT*128
    float* Pr   = Pd + (size_t)N_ENT * DIM;             // N_REL*128
    float* relp = Pr + N_REL * DIM;                     // N_REL*128
    int* rcnt      = (int*)(relp + N_REL * DIM);        // 240 (padded)
    int* rrow      = rcnt + 240;                        // 240
    int* rcursor   = rrow + 240;                        // 240
    int* row_start = rcursor + 240;                     // N_ENT+1
    int* cursor    = row_start + N_ENT + 1;             // N_ENT (hist cnt, then cursor)
    int* bsum      = cursor + N_ENT;                    // 128
    int* sdst      = bsum + 128;                        // NE
    int* srel      = sdst + NE;                         // NE
    int* rsrc      = srel + NE;                         // NE
    int* rdst      = rsrc + NE;                         // NE

    hipMemsetAsync(cursor, 0, N_ENT * sizeof(int), stream);
    hipMemsetAsync(relp, 0, (N_REL * DIM + 240) * sizeof(float), stream);  // relp + rcnt

    k_transpose_wa<<<192, 256, 0, stream>>>(Wa, WaT);
    k_proj_rel<<<(N_REL * DIM + 255) / 256, 256, 0, stream>>>(rele, Wa, ba, Pr);
    k_proj_ent<<<(N_ENT + 63) / 64, 256, 0, stream>>>(ent, WaT, Ps, Pd);

    k_hist2<<<(NE + 255) / 256, 256, 0, stream>>>(trip, cursor, rcnt);
    k_scan1<<<98, 256, 0, stream>>>(cursor, row_start, bsum);
    k_scan2<<<1, 128, 0, stream>>>(bsum);
    k_scan3<<<(N_ENT + 256) / 256, 256, 0, stream>>>(row_start, bsum, cursor);
    k_relscan<<<1, 256, 0, stream>>>(rcnt, rrow, rcursor);
    k_scatter2<<<(NE + 255) / 256, 256, 0, stream>>>(trip, cursor, rcursor,
                                                     sdst, srel, rsrc, rdst);

    k_seg<<<(N_ENT + 3) / 4, 256, 0, stream>>>(row_start, sdst, srel, Ps, Pd, Pr,
                                               Wa2, ba2, out);
    k_relseg<<<(NE / CHUNK + 3) / 4, 256, 0, stream>>>(rrow, rsrc, rdst, Ps, Pd, Pr,
                                                       Wa2, ba2, relp);
    k_rel_final<<<(N_REL * DIM + 255) / 256, 256, 0, stream>>>(out, relp, rcnt);
}

// Round 4
// 459.766 us; speedup vs baseline: 1.3885x; 1.3885x over previous
//
#include <hip/hip_runtime.h>
#include <math.h>

// Problem constants (from reference)
#define N_ENT 100000
#define N_REL 237
#define DIM   128
#define NE    400000

// ---------------------------------------------------------------------------
// Pipeline:
//  1. Per-node projections: Ps = ent@Wa[:,0:128]^T, Pd = ent@Wa[:,256:384]^T,
//     Pr = rel@Wa[:,128:256]^T + ba  (6x fewer FLOPs than per-edge GEMM).
//  2. Build src-CSR and rel-CSR. Rel side uses BLOCK-AGGREGATED reservation:
//     per-block LDS histogram -> one global atomicAdd per (block,rel) chunk
//     (~92k atomics, 391-deep) instead of per-edge (400k, 1688-deep) which
//     cost 212us in round 3.
//  3. k_seg: one wave per src entity, register accumulate, finalize ELU(acc/ebs)
//     in-kernel. Zero global atomics.
//  4. k_relseg2: one 1024-thr block per rel (16 waves, edges wave-strided),
//     register accumulate + LDS cross-wave reduce + fused divide/ELU -> out.
//     Zero global atomics, no relp buffer.
// ---------------------------------------------------------------------------

__global__ void k_transpose_wa(const float* __restrict__ Wa, float* __restrict__ WaT) {
    int i = blockIdx.x * 256 + threadIdx.x;
    if (i < 384 * 128) {
        int k = i >> 7, j = i & 127;
        WaT[i] = Wa[j * 384 + k];   // WaT[k][j] = Wa[j][k]
    }
}

__global__ void k_proj_rel(const float* __restrict__ rel_e, const float* __restrict__ Wa,
                           const float* __restrict__ ba, float* __restrict__ Pr) {
    int i = blockIdx.x * 256 + threadIdx.x;
    if (i >= N_REL * DIM) return;
    int r = i >> 7, j = i & 127;
    float acc = ba[j];
    const float* wrow = Wa + j * 384 + 128;   // middle segment
    const float* erow = rel_e + r * DIM;
    #pragma unroll 8
    for (int k = 0; k < DIM; ++k) acc += erow[k] * wrow[k];
    Pr[i] = acc;
}

// Fused P_s / P_d projection (fp32 vector FMA; no fp32 MFMA on CDNA4).
#define KC 16
__global__ __launch_bounds__(256) void k_proj_ent(const float* __restrict__ ent,
        const float* __restrict__ WaT, float* __restrict__ Ps, float* __restrict__ Pd) {
    __shared__ float tile[64 * 132];          // 33.8 KB
    __shared__ float wsh[2 * KC * 128];       // 16 KB
    const int tid = threadIdx.x;
    const int row0 = blockIdx.x * 64;

    for (int i = tid; i < 64 * 32; i += 256) {
        int r = i >> 5, c4 = i & 31;
        float4 v = make_float4(0.f, 0.f, 0.f, 0.f);
        if (row0 + r < N_ENT) v = *(const float4*)(ent + (size_t)(row0 + r) * DIM + c4 * 4);
        *(float4*)(tile + r * 132 + c4 * 4) = v;
    }

    const int rg = tid >> 4, cg = tid & 15;
    const int r0 = rg * 4, j0 = cg * 8;

    float accs[4][8], accd[4][8];
    #pragma unroll
    for (int i = 0; i < 4; ++i)
        #pragma unroll
        for (int j = 0; j < 8; ++j) { accs[i][j] = 0.f; accd[i][j] = 0.f; }

    for (int kc = 0; kc < DIM; kc += KC) {
        __syncthreads();
        for (int i = tid; i < KC * 32; i += 256) {
            int kk = i >> 5, c4 = i & 31;
            *(float4*)(wsh + kk * 128 + c4 * 4) =
                *(const float4*)(WaT + (kc + kk) * 128 + c4 * 4);
            *(float4*)(wsh + KC * 128 + kk * 128 + c4 * 4) =
                *(const float4*)(WaT + (256 + kc + kk) * 128 + c4 * 4);
        }
        __syncthreads();
        #pragma unroll
        for (int kk = 0; kk < KC; ++kk) {
            float4 a0 = *(float4*)(wsh + kk * 128 + j0);
            float4 a1 = *(float4*)(wsh + kk * 128 + j0 + 4);
            float4 b0 = *(float4*)(wsh + KC * 128 + kk * 128 + j0);
            float4 b1 = *(float4*)(wsh + KC * 128 + kk * 128 + j0 + 4);
            float ws[8] = {a0.x, a0.y, a0.z, a0.w, a1.x, a1.y, a1.z, a1.w};
            float wd[8] = {b0.x, b0.y, b0.z, b0.w, b1.x, b1.y, b1.z, b1.w};
            #pragma unroll
            for (int i = 0; i < 4; ++i) {
                float e = tile[(r0 + i) * 132 + kc + kk];
                #pragma unroll
                for (int j = 0; j < 8; ++j) {
                    accs[i][j] += e * ws[j];
                    accd[i][j] += e * wd[j];
                }
            }
        }
    }

    #pragma unroll
    for (int i = 0; i < 4; ++i) {
        int row = row0 + r0 + i;
        if (row < N_ENT) {
            float4 o;
            o = make_float4(accs[i][0], accs[i][1], accs[i][2], accs[i][3]);
            *(float4*)(Ps + (size_t)row * DIM + j0) = o;
            o = make_float4(accs[i][4], accs[i][5], accs[i][6], accs[i][7]);
            *(float4*)(Ps + (size_t)row * DIM + j0 + 4) = o;
            o = make_float4(accd[i][0], accd[i][1], accd[i][2], accd[i][3]);
            *(float4*)(Pd + (size_t)row * DIM + j0) = o;
            o = make_float4(accd[i][4], accd[i][5], accd[i][6], accd[i][7]);
            *(float4*)(Pd + (size_t)row * DIM + j0 + 4) = o;
        }
    }
}

// ---------------- CSR build ----------------
// 1024 edges per block: src histogram (global atomics, 100k addrs) + rel
// histogram (LDS) flushed once per block.
__global__ void k_hist2(const int* __restrict__ trip, int* __restrict__ scnt,
                        int* __restrict__ rcnt) {
    __shared__ int lh[N_REL];
    for (int i = threadIdx.x; i < N_REL; i += 256) lh[i] = 0;
    __syncthreads();
    int e0 = blockIdx.x * 1024 + threadIdx.x * 4;
    #pragma unroll
    for (int k = 0; k < 4; ++k) {
        int e = e0 + k;
        if (e < NE) {
            atomicAdd(scnt + trip[3 * e], 1);
            atomicAdd(&lh[trip[3 * e + 2]], 1);
        }
    }
    __syncthreads();
    for (int i = threadIdx.x; i < N_REL; i += 256)
        if (lh[i]) atomicAdd(rcnt + i, lh[i]);
}

// 98 blocks x 256 thr; each thread owns 4 consecutive entries.
__global__ void k_scan1(const int* __restrict__ cnt, int* __restrict__ escan,
                        int* __restrict__ bsum) {
    __shared__ int sh[256];
    const int t = threadIdx.x;
    int base = blockIdx.x * 1024 + t * 4;
    int v[4]; int s = 0;
    #pragma unroll
    for (int k = 0; k < 4; ++k) { int idx = base + k; v[k] = (idx < N_ENT) ? cnt[idx] : 0; s += v[k]; }
    sh[t] = s; __syncthreads();
    for (int off = 1; off < 256; off <<= 1) {
        int u = (t >= off) ? sh[t - off] : 0;
        __syncthreads();
        sh[t] += u;
        __syncthreads();
    }
    int run = sh[t] - s;
    #pragma unroll
    for (int k = 0; k < 4; ++k) { int idx = base + k; if (idx < N_ENT) escan[idx] = run; run += v[k]; }
    if (t == 255) bsum[blockIdx.x] = sh[255];
}

__global__ void k_scan2(int* __restrict__ bsum) {   // 1 block, exclusive over 98
    __shared__ int sh[128];
    const int t = threadIdx.x;
    int v = (t < 98) ? bsum[t] : 0;
    sh[t] = v; __syncthreads();
    for (int off = 1; off < 128; off <<= 1) {
        int u = (t >= off) ? sh[t - off] : 0;
        __syncthreads();
        sh[t] += u;
        __syncthreads();
    }
    if (t < 98) bsum[t] = sh[t] - v;
}

__global__ void k_scan3(int* __restrict__ row_start, const int* __restrict__ bsum,
                        int* __restrict__ cursor) {
    int i = blockIdx.x * 256 + threadIdx.x;
    if (i < N_ENT) {
        int v = row_start[i] + bsum[i >> 10];
        row_start[i] = v;
        cursor[i] = v;
    } else if (i == N_ENT) {
        row_start[N_ENT] = NE;
    }
}

// single block: exclusive scan of rcnt[237] -> rrow, init rcursor; rrow[237]=NE
__global__ void k_relscan(const int* __restrict__ rcnt, int* __restrict__ rrow,
                          int* __restrict__ rcursor) {
    __shared__ int sh[256];
    const int t = threadIdx.x;
    int v = (t < N_REL) ? rcnt[t] : 0;
    sh[t] = v; __syncthreads();
    for (int off = 1; off < 256; off <<= 1) {
        int u = (t >= off) ? sh[t - off] : 0;
        __syncthreads();
        sh[t] += u;
        __syncthreads();
    }
    int excl = sh[t] - v;
    if (t <= N_REL) rrow[t] = excl;
    if (t < N_REL) rcursor[t] = excl;
}

// Scatter building BOTH CSRs. Rel side: block-aggregated reservation to avoid
// 237-address per-edge atomic contention (round-3 lesson: 212us!).
__global__ __launch_bounds__(256) void k_scatter3(const int* __restrict__ trip,
        int* __restrict__ scursor, int* __restrict__ rcursor,
        int* __restrict__ sdst, int* __restrict__ srel,
        int* __restrict__ rsrc, int* __restrict__ rdst) {
    __shared__ int lh[N_REL];     // hist, then intra-block cursor
    __shared__ int lbase[N_REL];  // reserved global base per rel
    const int t = threadIdx.x;
    for (int i = t; i < N_REL; i += 256) lh[i] = 0;
    __syncthreads();

    const int e0 = blockIdx.x * 1024 + t * 4;
    int sv[4], dv[4], rv[4];
    #pragma unroll
    for (int k = 0; k < 4; ++k) {
        int e = e0 + k;
        if (e < NE) {
            sv[k] = trip[3 * e]; dv[k] = trip[3 * e + 1]; rv[k] = trip[3 * e + 2];
            atomicAdd(&lh[rv[k]], 1);
        } else { sv[k] = -1; }
    }
    __syncthreads();
    for (int i = t; i < N_REL; i += 256) {
        int c = lh[i];
        lbase[i] = c ? atomicAdd(rcursor + i, c) : 0;
        lh[i] = 0;   // reuse as intra-block cursor
    }
    __syncthreads();
    #pragma unroll
    for (int k = 0; k < 4; ++k) {
        if (sv[k] >= 0) {
            int p1 = atomicAdd(scursor + sv[k], 1);
            sdst[p1] = dv[k];
            srel[p1] = rv[k];
            int intra = atomicAdd(&lh[rv[k]], 1);
            int p2 = lbase[rv[k]] + intra;
            rsrc[p2] = sv[k];
            rdst[p2] = dv[k];
        }
    }
}

// ---------------- main segment kernels ----------------
// One wave per src entity; zero global atomics; fused finalize.
__global__ __launch_bounds__(256) void k_seg(const int* __restrict__ row_start,
        const int* __restrict__ sdst, const int* __restrict__ srel,
        const float* __restrict__ Ps, const float* __restrict__ Pd, const float* __restrict__ Pr,
        const float* __restrict__ Wa2, const float* __restrict__ ba2,
        float* __restrict__ out) {
    const int lane = threadIdx.x & 63;
    const int s = (blockIdx.x * 256 + threadIdx.x) >> 6;
    if (s >= N_ENT) return;
    const float w0 = Wa2[lane], w1 = Wa2[64 + lane];
    const float bb = ba2[0];

    const int beg = row_start[s], end = row_start[s + 1];
    const float ps0 = Ps[(size_t)s * DIM + lane];
    const float ps1 = Ps[(size_t)s * DIM + 64 + lane];

    float acc0 = 0.f, acc1 = 0.f, ebs = 0.f;
    for (int j = beg; j < end; ++j) {
        int d = sdst[j];
        int r = srel[j];
        float c0 = ps0 + Pr[r * DIM + lane]      + Pd[(size_t)d * DIM + lane];
        float c1 = ps1 + Pr[r * DIM + 64 + lane] + Pd[(size_t)d * DIM + 64 + lane];
        float p = c0 * w0 + c1 * w1;
        #pragma unroll
        for (int off = 32; off > 0; off >>= 1) p += __shfl_xor(p, off, 64);
        float b = p + bb;
        b = (b > 0.f) ? b : 0.01f * b;        // leaky_relu slope 0.01
        float eb = expf(b);
        acc0 += eb * c0; acc1 += eb * c1; ebs += eb;
    }

    float ebsv = (ebs == 0.f) ? 1e-12f : ebs;
    float h0 = acc0 / ebsv, h1 = acc1 / ebsv;
    out[(size_t)s * DIM + lane]      = (h0 > 0.f) ? h0 : expm1f(h0);  // elu
    out[(size_t)s * DIM + 64 + lane] = (h1 > 0.f) ? h1 : expm1f(h1);
}

// One block (1024 thr = 16 waves) per rel; edges wave-strided; LDS reduce;
// fused divide + ELU directly into out. No atomics, no relp buffer.
__global__ __launch_bounds__(1024) void k_relseg2(const int* __restrict__ rrow,
        const int* __restrict__ rcnt,
        const int* __restrict__ rsrc, const int* __restrict__ rdst,
        const float* __restrict__ Ps, const float* __restrict__ Pd, const float* __restrict__ Pr,
        const float* __restrict__ Wa2, const float* __restrict__ ba2,
        float* __restrict__ out) {
    __shared__ float red[16 * 128];
    const int r = blockIdx.x;
    const int t = threadIdx.x;
    const int lane = t & 63;
    const int w = t >> 6;                 // wave 0..15
    const float w0 = Wa2[lane], w1 = Wa2[64 + lane];
    const float bb = ba2[0];

    const int beg = rrow[r], end = rrow[r + 1];
    const float pr0 = Pr[r * DIM + lane];
    const float pr1 = Pr[r * DIM + 64 + lane];

    float a0 = 0.f, a1 = 0.f;
    for (int j = beg + w; j < end; j += 16) {
        int s = rsrc[j], d = rdst[j];
        float c0 = pr0 + Ps[(size_t)s * DIM + lane]      + Pd[(size_t)d * DIM + lane];
        float c1 = pr1 + Ps[(size_t)s * DIM + 64 + lane] + Pd[(size_t)d * DIM + 64 + lane];
        float p = c0 * w0 + c1 * w1;
        #pragma unroll
        for (int off = 32; off > 0; off >>= 1) p += __shfl_xor(p, off, 64);
        float b = p + bb;
        b = (b > 0.f) ? b : 0.01f * b;
        float eb = expf(b);
        a0 += eb * c0; a1 += eb * c1;
    }
    red[w * 128 + lane]      = a0;
    red[w * 128 + 64 + lane] = a1;
    __syncthreads();
    if (t < 128) {
        float s = 0.f;
        #pragma unroll
        for (int ww = 0; ww < 16; ++ww) s += red[ww * 128 + t];
        float h = s / fmaxf((float)rcnt[r], 1.0f);
        out[(size_t)N_ENT * DIM + r * DIM + t] = (h > 0.f) ? h : expm1f(h);
    }
}

extern "C" void kernel_launch(void* const* d_in, const int* in_sizes, int n_in,
                              void* d_out, int out_size, void* d_ws, size_t ws_size,
                              hipStream_t stream) {
    const int*   trip = (const int*)d_in[0];
    const float* ent  = (const float*)d_in[1];
    const float* rele = (const float*)d_in[2];
    const float* Wa   = (const float*)d_in[3];
    const float* ba   = (const float*)d_in[4];
    const float* Wa2  = (const float*)d_in[5];
    const float* ba2  = (const float*)d_in[6];
    float* out = (float*)d_out;

    float* ws  = (float*)d_ws;
    float* WaT = ws;                                    // 384*128
    float* Ps  = WaT + 384 * 128;                       // N_ENT*128
    float* Pd  = Ps + (size_t)N_ENT * DIM;              // N_ENT*128
    float* Pr  = Pd + (size_t)N_ENT * DIM;              // N_REL*128
    int* row_start = (int*)(Pr + N_REL * DIM);          // N_ENT+1
    int* cursor    = row_start + N_ENT + 1;             // N_ENT   \ one memset
    int* rcnt      = cursor + N_ENT;                    // 240     /
    int* rrow      = rcnt + 240;                        // 240
    int* rcursor   = rrow + 240;                        // 240
    int* bsum      = rcursor + 240;                     // 128
    int* sdst      = bsum + 128;                        // NE
    int* srel      = sdst + NE;                         // NE
    int* rsrc      = srel + NE;                         // NE
    int* rdst      = rsrc + NE;                         // NE

    hipMemsetAsync(cursor, 0, (N_ENT + 240) * sizeof(int), stream);  // cursor + rcnt

    k_transpose_wa<<<192, 256, 0, stream>>>(Wa, WaT);
    k_proj_rel<<<(N_REL * DIM + 255) / 256, 256, 0, stream>>>(rele, Wa, ba, Pr);
    k_proj_ent<<<(N_ENT + 63) / 64, 256, 0, stream>>>(ent, WaT, Ps, Pd);

    k_hist2<<<(NE + 1023) / 1024, 256, 0, stream>>>(trip, cursor, rcnt);
    k_scan1<<<98, 256, 0, stream>>>(cursor, row_start, bsum);
    k_scan2<<<1, 128, 0, stream>>>(bsum);
    k_scan3<<<(N_ENT + 256) / 256, 256, 0, stream>>>(row_start, bsum, cursor);
    k_relscan<<<1, 256, 0, stream>>>(rcnt, rrow, rcursor);
    k_scatter3<<<(NE + 1023) / 1024, 256, 0, stream>>>(trip, cursor, rcursor,
                                                       sdst, srel, rsrc, rdst);

    k_seg<<<(N_ENT + 3) / 4, 256, 0, stream>>>(row_start, sdst, srel, Ps, Pd, Pr,
                                               Wa2, ba2, out);
    k_relseg2<<<N_REL, 1024, 0, stream>>>(rrow, rcnt, rsrc, rdst, Ps, Pd, Pr,
                                          Wa2, ba2, out);
}

// Round 6
// 432.935 us; speedup vs baseline: 1.4745x; 1.0620x over previous
//
#include <hip/hip_runtime.h>
#include <math.h>

// Problem constants (from reference)
#define N_ENT 100000
#define N_REL 237
#define DIM   128
#define NE    400000

// ---------------------------------------------------------------------------
// Pipeline:
//  1. Per-node projections (6x fewer FLOPs than per-edge GEMM):
//     Ps=ent@Wa[:,0:128]^T, Pd=ent@Wa[:,256:384]^T, Pr=rel@Wa[:,128:256]^T+ba.
//     k_proj_ent v2: weights LDS-staged DE-INTERLEAVED (4-way->2-way bank),
//     A read from global (L1-resident 32KB/block) -> LDS 50KB->16.9KB, occ up.
//     Epilogue fuses qs=Ps.w2, qd=Pd.w2 (edge-logit scalars).
//  2. src-CSR + rel-CSR build (block-aggregated rel reservation — round-3
//     lesson: 237-address per-edge atomics = 212us).
//  3. k_seg: one wave per src entity. Per edge: eb=exp(leaky(qs+qr+qd)) —
//     3 scalar broadcasts, NO dot/shfl — then acc += eb*(Pr[r]+Pd[d]).
//     h = ELU(ps + acc/ebs). Zero atomics.
//  4. k_relseg2: one 1024-thr block per rel; Σeb*c = Σeb*(Ps[s]+Pd[d]) +
//     (Σeb)*Pr[r]; LDS cross-wave reduce; fused /cnt + ELU. Zero atomics.
//     ROUND-5 BUG FIX: ebs is a per-WAVE scalar (all 64 lanes process the
//     same edge and hold identical ebs) — do NOT shfl-reduce it (was 64x).
// ---------------------------------------------------------------------------

__global__ void k_transpose_wa(const float* __restrict__ Wa, float* __restrict__ WaT) {
    int i = blockIdx.x * 256 + threadIdx.x;
    if (i < 384 * 128) {
        int k = i >> 7, j = i & 127;
        WaT[i] = Wa[j * 384 + k];   // WaT[k][j] = Wa[j][k]
    }
}

__global__ void k_proj_rel(const float* __restrict__ rel_e, const float* __restrict__ Wa,
                           const float* __restrict__ ba, float* __restrict__ Pr) {
    int i = blockIdx.x * 256 + threadIdx.x;
    if (i >= N_REL * DIM) return;
    int r = i >> 7, j = i & 127;
    float acc = ba[j];
    const float* wrow = Wa + j * 384 + 128;   // middle segment
    const float* erow = rel_e + r * DIM;
    #pragma unroll 8
    for (int k = 0; k < DIM; ++k) acc += erow[k] * wrow[k];
    Pr[i] = acc;
}

// qr[r] = Pr[r].w2 + ba2  (bias folded once here; qs/qd carry no bias)
__global__ void k_qr(const float* __restrict__ Pr, const float* __restrict__ Wa2,
                     const float* __restrict__ ba2, float* __restrict__ qr) {
    const int lane = threadIdx.x & 63;
    const int r = (blockIdx.x * 256 + threadIdx.x) >> 6;
    if (r >= N_REL) return;
    float p = Pr[r * DIM + lane] * Wa2[lane] + Pr[r * DIM + 64 + lane] * Wa2[64 + lane];
    #pragma unroll
    for (int off = 32; off > 0; off >>= 1) p += __shfl_xor(p, off, 64);
    if (lane == 0) qr[r] = p + ba2[0];
}

// Fused P_s/P_d projection, fp32 VALU (no fp32 MFMA on CDNA4).
// LDS: only de-interleaved weight slices (2 x 16 x 132 floats = 16.9 KB).
#define KC 16
__global__ __launch_bounds__(256) void k_proj_ent(const float* __restrict__ ent,
        const float* __restrict__ WaT, const float* __restrict__ Wa2,
        float* __restrict__ Ps, float* __restrict__ Pd,
        float* __restrict__ qs, float* __restrict__ qd) {
    __shared__ float wsh[2 * KC * 132];
    const int tid = threadIdx.x;
    const int row0 = blockIdx.x * 64;
    const int rg = tid >> 4, cg = tid & 15;
    const int r0 = rg * 4, j0 = cg * 8;

    int rows[4];
    #pragma unroll
    for (int i = 0; i < 4; ++i) {
        int rr = row0 + r0 + i;
        rows[i] = (rr < N_ENT) ? rr : (N_ENT - 1);   // clamp; guarded at write
    }

    float accs[4][8], accd[4][8];
    #pragma unroll
    for (int i = 0; i < 4; ++i)
        #pragma unroll
        for (int j = 0; j < 8; ++j) { accs[i][j] = 0.f; accd[i][j] = 0.f; }

    for (int kc = 0; kc < DIM; kc += KC) {
        if (kc) __syncthreads();
        // stage: 1024 float4 (s+d slices), de-interleaved chunk placement
        for (int u = tid; u < 2 * KC * 32; u += 256) {
            int m   = u >> 9;          // 0 = s-slice, 1 = d-slice
            int rem = u & 511;
            int kk  = rem >> 5, c4 = rem & 31;
            float4 v = *(const float4*)(WaT + (size_t)((m ? 256 : 0) + kc + kk) * 128 + c4 * 4);
            int perm = (c4 >> 1) + (c4 & 1) * 16;
            *(float4*)(wsh + m * KC * 132 + kk * 132 + perm * 4) = v;
        }
        __syncthreads();

        #pragma unroll
        for (int kq = 0; kq < 4; ++kq) {
            float ev[4][4];
            #pragma unroll
            for (int i = 0; i < 4; ++i) {
                float4 t = *(const float4*)(ent + (size_t)rows[i] * DIM + kc + kq * 4);
                ev[i][0] = t.x; ev[i][1] = t.y; ev[i][2] = t.z; ev[i][3] = t.w;
            }
            #pragma unroll
            for (int kk2 = 0; kk2 < 4; ++kk2) {
                int kk = kq * 4 + kk2;
                float4 a0 = *(float4*)(wsh + kk * 132 + cg * 4);
                float4 a1 = *(float4*)(wsh + kk * 132 + 64 + cg * 4);
                float4 b0 = *(float4*)(wsh + KC * 132 + kk * 132 + cg * 4);
                float4 b1 = *(float4*)(wsh + KC * 132 + kk * 132 + 64 + cg * 4);
                float ws[8] = {a0.x, a0.y, a0.z, a0.w, a1.x, a1.y, a1.z, a1.w};
                float wd[8] = {b0.x, b0.y, b0.z, b0.w, b1.x, b1.y, b1.z, b1.w};
                #pragma unroll
                for (int i = 0; i < 4; ++i) {
                    float e = ev[i][kk2];
                    #pragma unroll
                    for (int j = 0; j < 8; ++j) {
                        accs[i][j] += e * ws[j];
                        accd[i][j] += e * wd[j];
                    }
                }
            }
        }
    }

    // write Ps/Pd
    #pragma unroll
    for (int i = 0; i < 4; ++i) {
        int row = row0 + r0 + i;
        if (row < N_ENT) {
            float4 o;
            o = make_float4(accs[i][0], accs[i][1], accs[i][2], accs[i][3]);
            *(float4*)(Ps + (size_t)row * DIM + j0) = o;
            o = make_float4(accs[i][4], accs[i][5], accs[i][6], accs[i][7]);
            *(float4*)(Ps + (size_t)row * DIM + j0 + 4) = o;
            o = make_float4(accd[i][0], accd[i][1], accd[i][2], accd[i][3]);
            *(float4*)(Pd + (size_t)row * DIM + j0) = o;
            o = make_float4(accd[i][4], accd[i][5], accd[i][6], accd[i][7]);
            *(float4*)(Pd + (size_t)row * DIM + j0 + 4) = o;
        }
    }

    // fused qs/qd: partial dot with w2 over this thread's 8 cols, LDS reduce
    __syncthreads();                 // wsh readers done; reuse as reduce buffer
    float4 w2a = *(const float4*)(Wa2 + j0);
    float4 w2b = *(const float4*)(Wa2 + j0 + 4);
    float w2v[8] = {w2a.x, w2a.y, w2a.z, w2a.w, w2b.x, w2b.y, w2b.z, w2b.w};
    #pragma unroll
    for (int i = 0; i < 4; ++i) {
        float p_s = 0.f, p_d = 0.f;
        #pragma unroll
        for (int j = 0; j < 8; ++j) { p_s += accs[i][j] * w2v[j]; p_d += accd[i][j] * w2v[j]; }
        wsh[(r0 + i) * 16 + cg]        = p_s;
        wsh[1024 + (r0 + i) * 16 + cg] = p_d;
    }
    __syncthreads();
    if (tid < 64) {
        int row = row0 + tid;
        if (row < N_ENT) {
            float ss = 0.f, sd = 0.f;
            #pragma unroll
            for (int c = 0; c < 16; ++c) {
                ss += wsh[tid * 16 + c];
                sd += wsh[1024 + tid * 16 + c];
            }
            qs[row] = ss;
            qd[row] = sd;
        }
    }
}

// ---------------- CSR build ----------------
__global__ void k_hist2(const int* __restrict__ trip, int* __restrict__ scnt,
                        int* __restrict__ rcnt) {
    __shared__ int lh[N_REL];
    for (int i = threadIdx.x; i < N_REL; i += 256) lh[i] = 0;
    __syncthreads();
    int e0 = blockIdx.x * 1024 + threadIdx.x * 4;
    #pragma unroll
    for (int k = 0; k < 4; ++k) {
        int e = e0 + k;
        if (e < NE) {
            atomicAdd(scnt + trip[3 * e], 1);
            atomicAdd(&lh[trip[3 * e + 2]], 1);
        }
    }
    __syncthreads();
    for (int i = threadIdx.x; i < N_REL; i += 256)
        if (lh[i]) atomicAdd(rcnt + i, lh[i]);
}

__global__ void k_scan1(const int* __restrict__ cnt, int* __restrict__ escan,
                        int* __restrict__ bsum) {
    __shared__ int sh[256];
    const int t = threadIdx.x;
    int base = blockIdx.x * 1024 + t * 4;
    int v[4]; int s = 0;
    #pragma unroll
    for (int k = 0; k < 4; ++k) { int idx = base + k; v[k] = (idx < N_ENT) ? cnt[idx] : 0; s += v[k]; }
    sh[t] = s; __syncthreads();
    for (int off = 1; off < 256; off <<= 1) {
        int u = (t >= off) ? sh[t - off] : 0;
        __syncthreads();
        sh[t] += u;
        __syncthreads();
    }
    int run = sh[t] - s;
    #pragma unroll
    for (int k = 0; k < 4; ++k) { int idx = base + k; if (idx < N_ENT) escan[idx] = run; run += v[k]; }
    if (t == 255) bsum[blockIdx.x] = sh[255];
}

__global__ void k_scan2(int* __restrict__ bsum) {
    __shared__ int sh[128];
    const int t = threadIdx.x;
    int v = (t < 98) ? bsum[t] : 0;
    sh[t] = v; __syncthreads();
    for (int off = 1; off < 128; off <<= 1) {
        int u = (t >= off) ? sh[t - off] : 0;
        __syncthreads();
        sh[t] += u;
        __syncthreads();
    }
    if (t < 98) bsum[t] = sh[t] - v;
}

__global__ void k_scan3(int* __restrict__ row_start, const int* __restrict__ bsum,
                        int* __restrict__ cursor) {
    int i = blockIdx.x * 256 + threadIdx.x;
    if (i < N_ENT) {
        int v = row_start[i] + bsum[i >> 10];
        row_start[i] = v;
        cursor[i] = v;
    } else if (i == N_ENT) {
        row_start[N_ENT] = NE;
    }
}

__global__ void k_relscan(const int* __restrict__ rcnt, int* __restrict__ rrow,
                          int* __restrict__ rcursor) {
    __shared__ int sh[256];
    const int t = threadIdx.x;
    int v = (t < N_REL) ? rcnt[t] : 0;
    sh[t] = v; __syncthreads();
    for (int off = 1; off < 256; off <<= 1) {
        int u = (t >= off) ? sh[t - off] : 0;
        __syncthreads();
        sh[t] += u;
        __syncthreads();
    }
    int excl = sh[t] - v;
    if (t <= N_REL) rrow[t] = excl;
    if (t < N_REL) rcursor[t] = excl;
}

// Scatter both CSRs; rel side block-aggregated (round-3 lesson). int2 payloads.
__global__ __launch_bounds__(256) void k_scatter3(const int* __restrict__ trip,
        int* __restrict__ scursor, int* __restrict__ rcursor,
        int2* __restrict__ sdr, int2* __restrict__ rsd) {
    __shared__ int lh[N_REL];
    __shared__ int lbase[N_REL];
    const int t = threadIdx.x;
    for (int i = t; i < N_REL; i += 256) lh[i] = 0;
    __syncthreads();

    const int e0 = blockIdx.x * 1024 + t * 4;
    int sv[4], dv[4], rv[4];
    #pragma unroll
    for (int k = 0; k < 4; ++k) {
        int e = e0 + k;
        if (e < NE) {
            sv[k] = trip[3 * e]; dv[k] = trip[3 * e + 1]; rv[k] = trip[3 * e + 2];
            atomicAdd(&lh[rv[k]], 1);
        } else { sv[k] = -1; }
    }
    __syncthreads();
    for (int i = t; i < N_REL; i += 256) {
        int c = lh[i];
        lbase[i] = c ? atomicAdd(rcursor + i, c) : 0;
        lh[i] = 0;
    }
    __syncthreads();
    #pragma unroll
    for (int k = 0; k < 4; ++k) {
        if (sv[k] >= 0) {
            int p1 = atomicAdd(scursor + sv[k], 1);
            sdr[p1] = make_int2(dv[k], rv[k]);
            int intra = atomicAdd(&lh[rv[k]], 1);
            rsd[lbase[rv[k]] + intra] = make_int2(sv[k], dv[k]);
        }
    }
}

// ---------------- main segment kernels ----------------
// One wave per src entity; eb from scalar logits; zero atomics.
__global__ __launch_bounds__(256) void k_seg(const int* __restrict__ row_start,
        const int2* __restrict__ sdr,
        const float* __restrict__ Ps, const float* __restrict__ Pd, const float* __restrict__ Pr,
        const float* __restrict__ qs, const float* __restrict__ qd, const float* __restrict__ qr,
        float* __restrict__ out) {
    const int lane = threadIdx.x & 63;
    const int s = (blockIdx.x * 256 + threadIdx.x) >> 6;
    if (s >= N_ENT) return;

    const int beg = row_start[s], end = row_start[s + 1];
    if (beg == end) {                       // degree 0: h_sum=0 -> elu(0)=0
        out[(size_t)s * DIM + lane] = 0.f;
        out[(size_t)s * DIM + 64 + lane] = 0.f;
        return;
    }
    const float myqs = qs[s];
    float acc0 = 0.f, acc1 = 0.f, ebs = 0.f;
    for (int j = beg; j < end; ++j) {
        int2 dr = sdr[j];                   // (dst, rel) broadcast
        float b = myqs + qr[dr.y] + qd[dr.x];
        b = (b > 0.f) ? b : 0.01f * b;      // leaky_relu slope 0.01
        float eb = expf(b);
        acc0 += eb * (Pr[dr.y * DIM + lane]      + Pd[(size_t)dr.x * DIM + lane]);
        acc1 += eb * (Pr[dr.y * DIM + 64 + lane] + Pd[(size_t)dr.x * DIM + 64 + lane]);
        ebs += eb;
    }
    // sum(eb*c)/ebs = ps + sum(eb*(pr+pd))/ebs   (ebs>0 since exp>0)
    float h0 = Ps[(size_t)s * DIM + lane]      + acc0 / ebs;
    float h1 = Ps[(size_t)s * DIM + 64 + lane] + acc1 / ebs;
    out[(size_t)s * DIM + lane]      = (h0 > 0.f) ? h0 : expm1f(h0);  // elu
    out[(size_t)s * DIM + 64 + lane] = (h1 > 0.f) ? h1 : expm1f(h1);
}

// One 1024-thr block (16 waves) per rel; scalar-logit eb; LDS reduce; fused ELU.
__global__ __launch_bounds__(1024) void k_relseg2(const int* __restrict__ rrow,
        const int2* __restrict__ rsd,
        const float* __restrict__ Ps, const float* __restrict__ Pd, const float* __restrict__ Pr,
        const float* __restrict__ qs, const float* __restrict__ qd, const float* __restrict__ qr,
        float* __restrict__ out) {
    __shared__ float red[16 * 128];
    __shared__ float reb[16];
    const int r = blockIdx.x;
    const int t = threadIdx.x;
    const int lane = t & 63;
    const int w = t >> 6;
    const float myqr = qr[r];

    const int beg = rrow[r], end = rrow[r + 1];
    float a0 = 0.f, a1 = 0.f, ebs = 0.f;
    for (int j = beg + w; j < end; j += 16) {
        int2 sd = rsd[j];                   // (src, dst) broadcast
        float b = myqr + qs[sd.x] + qd[sd.y];
        b = (b > 0.f) ? b : 0.01f * b;
        float eb = expf(b);
        a0 += eb * (Ps[(size_t)sd.x * DIM + lane]      + Pd[(size_t)sd.y * DIM + lane]);
        a1 += eb * (Ps[(size_t)sd.x * DIM + 64 + lane] + Pd[(size_t)sd.y * DIM + 64 + lane]);
        ebs += eb;
    }
    red[w * 128 + lane]      = a0;
    red[w * 128 + 64 + lane] = a1;
    // ebs is a per-WAVE scalar: every lane of the wave processed the SAME
    // edges, so ebs is already the wave's full sum. No shfl reduce (round-5
    // bug: reducing here multiplied Sum(e_b) by 64).
    if (lane == 0) reb[w] = ebs;
    __syncthreads();
    if (t < 128) {
        float ssum = 0.f, et = 0.f;
        #pragma unroll
        for (int ww = 0; ww < 16; ++ww) { ssum += red[ww * 128 + t]; et += reb[ww]; }
        // sum(eb*c) = sum(eb*(ps+pd)) + (sum eb)*pr
        float h = (ssum + et * Pr[r * DIM + t]) / fmaxf((float)(end - beg), 1.0f);
        out[(size_t)N_ENT * DIM + r * DIM + t] = (h > 0.f) ? h : expm1f(h);
    }
}

extern "C" void kernel_launch(void* const* d_in, const int* in_sizes, int n_in,
                              void* d_out, int out_size, void* d_ws, size_t ws_size,
                              hipStream_t stream) {
    const int*   trip = (const int*)d_in[0];
    const float* ent  = (const float*)d_in[1];
    const float* rele = (const float*)d_in[2];
    const float* Wa   = (const float*)d_in[3];
    const float* ba   = (const float*)d_in[4];
    const float* Wa2  = (const float*)d_in[5];
    const float* ba2  = (const float*)d_in[6];
    float* out = (float*)d_out;

    float* ws  = (float*)d_ws;
    float* WaT = ws;                                    // 384*128
    float* Ps  = WaT + 384 * 128;                       // N_ENT*128
    float* Pd  = Ps + (size_t)N_ENT * DIM;              // N_ENT*128
    float* Pr  = Pd + (size_t)N_ENT * DIM;              // N_REL*128
    float* qs  = Pr + N_REL * DIM;                      // N_ENT
    float* qd  = qs + N_ENT;                            // N_ENT
    float* qr  = qd + N_ENT;                            // 240
    int* row_start = (int*)(qr + 240);                  // N_ENT+1
    int* cursor    = row_start + N_ENT + 1;             // N_ENT   \ one memset
    int* rcnt      = cursor + N_ENT;                    // 240     /
    int* rrow      = rcnt + 240;                        // 240
    int* rcursor   = rrow + 240;                        // 240
    int* bsum      = rcursor + 240;                     // 128
    int2* sdr      = (int2*)(bsum + 128);               // NE int2
    int2* rsd      = sdr + NE;                          // NE int2

    hipMemsetAsync(cursor, 0, (N_ENT + 240) * sizeof(int), stream);  // cursor + rcnt

    k_transpose_wa<<<192, 256, 0, stream>>>(Wa, WaT);
    k_proj_rel<<<(N_REL * DIM + 255) / 256, 256, 0, stream>>>(rele, Wa, ba, Pr);
    k_qr<<<(N_REL * 64 + 255) / 256, 256, 0, stream>>>(Pr, Wa2, ba2, qr);
    k_proj_ent<<<(N_ENT + 63) / 64, 256, 0, stream>>>(ent, WaT, Wa2, Ps, Pd, qs, qd);

    k_hist2<<<(NE + 1023) / 1024, 256, 0, stream>>>(trip, cursor, rcnt);
    k_scan1<<<98, 256, 0, stream>>>(cursor, row_start, bsum);
    k_scan2<<<1, 128, 0, stream>>>(bsum);
    k_scan3<<<(N_ENT + 256) / 256, 256, 0, stream>>>(row_start, bsum, cursor);
    k_relscan<<<1, 256, 0, stream>>>(rcnt, rrow, rcursor);
    k_scatter3<<<(NE + 1023) / 1024, 256, 0, stream>>>(trip, cursor, rcursor, sdr, rsd);

    k_seg<<<(N_ENT + 3) / 4, 256, 0, stream>>>(row_start, sdr, Ps, Pd, Pr,
                                               qs, qd, qr, out);
    k_relseg2<<<N_REL, 1024, 0, stream>>>(rrow, rsd, Ps, Pd, Pr, qs, qd, qr, out);
}

// Round 7
// 389.617 us; speedup vs baseline: 1.6385x; 1.1112x over previous
//
#include <hip/hip_runtime.h>
#include <math.h>

// Problem constants (from reference)
#define N_ENT 100000
#define N_REL 237
#define DIM   128
#define NE    400000
#define SEGB  ((N_ENT + 15) / 16)   // seg blocks in fused edge kernel (16 waves/blk)

typedef short bf16x8 __attribute__((ext_vector_type(8)));   // 8 bf16 in 4 VGPRs
typedef float f32x4  __attribute__((ext_vector_type(4)));

// ---------------------------------------------------------------------------
// Pipeline:
//  1. Pr = rel@Wa[:,128:256]^T + ba (fp32, tiny).  vs/vd = Wa_seg^T . w2
//     (128-dim, so qs = ent.vs EXACT fp32 — e_b path is numerically identical
//     to the passing round-6 kernel; only Ps/Pd tables carry bf16 error).
//  2. k_proj_mfma: Ps/Pd via bf16 MFMA 16x16x32 (A = ent rows converted
//     in-register from fp32; B = bf16 Wa read contiguous-k — Wa IS B^T).
//     qs/qd accumulated fp32 from the same ent loads. No LDS.
//  3. CSR build (block-aggregated rel reservation — round-3 lesson).
//  4. k_edges: FUSED seg+rel gather kernel, rel blocks first (long poles),
//     seg blocks backfill; the two phases co-schedule instead of serializing.
// ---------------------------------------------------------------------------

__device__ __forceinline__ unsigned short f2bf(float f) {
    unsigned int u = __float_as_uint(f);
    u += 0x7FFF + ((u >> 16) & 1);          // RNE
    return (unsigned short)(u >> 16);
}

__global__ void k_wah(const float* __restrict__ Wa, unsigned short* __restrict__ Wah) {
    int i = blockIdx.x * 256 + threadIdx.x;
    if (i < 128 * 384) Wah[i] = f2bf(Wa[i]);
}

// vs[k] = sum_j Wa[j][k]*w2[j]; vd[k] = sum_j Wa[j][256+k]*w2[j]
__global__ void k_vsd(const float* __restrict__ Wa, const float* __restrict__ Wa2,
                      float* __restrict__ vs, float* __restrict__ vd) {
    int t = threadIdx.x;
    if (t < 128) {
        float a = 0.f;
        for (int j = 0; j < 128; ++j) a += Wa[j * 384 + t] * Wa2[j];
        vs[t] = a;
    } else if (t < 256) {
        int k = t - 128;
        float a = 0.f;
        for (int j = 0; j < 128; ++j) a += Wa[j * 384 + 256 + k] * Wa2[j];
        vd[k] = a;
    }
}

__global__ void k_proj_rel(const float* __restrict__ rel_e, const float* __restrict__ Wa,
                           const float* __restrict__ ba, float* __restrict__ Pr) {
    int i = blockIdx.x * 256 + threadIdx.x;
    if (i >= N_REL * DIM) return;
    int r = i >> 7, j = i & 127;
    float acc = ba[j];
    const float* wrow = Wa + j * 384 + 128;   // middle segment
    const float* erow = rel_e + r * DIM;
    #pragma unroll 8
    for (int k = 0; k < DIM; ++k) acc += erow[k] * wrow[k];
    Pr[i] = acc;
}

// qr[r] = Pr[r].w2 + ba2
__global__ void k_qr(const float* __restrict__ Pr, const float* __restrict__ Wa2,
                     const float* __restrict__ ba2, float* __restrict__ qr) {
    const int lane = threadIdx.x & 63;
    const int r = (blockIdx.x * 256 + threadIdx.x) >> 6;
    if (r >= N_REL) return;
    float p = Pr[r * DIM + lane] * Wa2[lane] + Pr[r * DIM + 64 + lane] * Wa2[64 + lane];
    #pragma unroll
    for (int off = 32; off > 0; off >>= 1) p += __shfl_xor(p, off, 64);
    if (lane == 0) qr[r] = p + ba2[0];
}

// bf16-MFMA projection. Per block: 4 waves, 64 rows. Per wave: 16 rows x 128
// cols of BOTH Ps and Pd (8 col-tiles x 2 mats x K=128/32 steps = 64 MFMA).
// A-frag: lane holds ent[row0+(l&15)][k0+(l>>4)*8 + 0..7] (fp32 load -> bf16).
// B-frag: lane holds Wa[col=t*16+(l&15)][k0+(l>>4)*8 + 0..7] (bf16x8 load).
// C/D: col=lane&15, row=(lane>>4)*4+reg (verified mapping).
// qs/qd: fp32 partials from the SAME fp32 ent loads (exact logit path).
__global__ __launch_bounds__(256) void k_proj_mfma(const float* __restrict__ ent,
        const unsigned short* __restrict__ Wah,
        const float* __restrict__ vs, const float* __restrict__ vd,
        float* __restrict__ Ps, float* __restrict__ Pd,
        float* __restrict__ qs, float* __restrict__ qd) {
    const int wave = threadIdx.x >> 6, lane = threadIdx.x & 63;
    const int row0 = blockIdx.x * 64 + wave * 16;
    const int lr = lane & 15;       // A-row / B-col / D-col
    const int lg = lane >> 4;       // k-group / D row-group
    const int arow = (row0 + lr < N_ENT) ? row0 + lr : (N_ENT - 1);  // clamp

    f32x4 accS[8], accD[8];
    #pragma unroll
    for (int t = 0; t < 8; ++t) {
        accS[t] = (f32x4){0.f, 0.f, 0.f, 0.f};
        accD[t] = (f32x4){0.f, 0.f, 0.f, 0.f};
    }
    float qsp = 0.f, qdp = 0.f;

    #pragma unroll
    for (int kk = 0; kk < 4; ++kk) {
        const int k0 = kk * 32 + lg * 8;
        const float* ep = ent + (size_t)arow * DIM + k0;
        float4 e0 = *(const float4*)ep;
        float4 e1 = *(const float4*)(ep + 4);
        // exact fp32 logit partials
        float4 v0 = *(const float4*)(vs + k0);
        float4 v1 = *(const float4*)(vs + k0 + 4);
        qsp += e0.x*v0.x + e0.y*v0.y + e0.z*v0.z + e0.w*v0.w
             + e1.x*v1.x + e1.y*v1.y + e1.z*v1.z + e1.w*v1.w;
        float4 u0 = *(const float4*)(vd + k0);
        float4 u1 = *(const float4*)(vd + k0 + 4);
        qdp += e0.x*u0.x + e0.y*u0.y + e0.z*u0.z + e0.w*u0.w
             + e1.x*u1.x + e1.y*u1.y + e1.z*u1.z + e1.w*u1.w;
        // A-frag bf16
        bf16x8 a;
        a[0] = (short)f2bf(e0.x); a[1] = (short)f2bf(e0.y);
        a[2] = (short)f2bf(e0.z); a[3] = (short)f2bf(e0.w);
        a[4] = (short)f2bf(e1.x); a[5] = (short)f2bf(e1.y);
        a[6] = (short)f2bf(e1.z); a[7] = (short)f2bf(e1.w);
        #pragma unroll
        for (int t = 0; t < 8; ++t) {
            const size_t wb = (size_t)(t * 16 + lr) * 384 + k0;
            bf16x8 bs = *(const bf16x8*)(Wah + wb);         // seg 0: Wa[col][k]
            bf16x8 bd = *(const bf16x8*)(Wah + wb + 256);   // seg 2
            accS[t] = __builtin_amdgcn_mfma_f32_16x16x32_bf16(a, bs, accS[t], 0, 0, 0);
            accD[t] = __builtin_amdgcn_mfma_f32_16x16x32_bf16(a, bd, accD[t], 0, 0, 0);
        }
    }

    // store Ps/Pd: row = row0 + lg*4 + q, col = t*16 + lr
    #pragma unroll
    for (int q = 0; q < 4; ++q) {
        const int row = row0 + lg * 4 + q;
        if (row < N_ENT) {
            #pragma unroll
            for (int t = 0; t < 8; ++t) {
                Ps[(size_t)row * DIM + t * 16 + lr] = accS[t][q];
                Pd[(size_t)row * DIM + t * 16 + lr] = accD[t][q];
            }
        }
    }

    // qs/qd: sum the 4 k-group partials (lanes differing in bits 4,5)
    qsp += __shfl_xor(qsp, 16, 64); qsp += __shfl_xor(qsp, 32, 64);
    qdp += __shfl_xor(qdp, 16, 64); qdp += __shfl_xor(qdp, 32, 64);
    if (lane < 16 && row0 + lane < N_ENT) {
        qs[row0 + lane] = qsp;
        qd[row0 + lane] = qdp;
    }
}

// ---------------- CSR build ----------------
__global__ void k_hist2(const int* __restrict__ trip, int* __restrict__ scnt,
                        int* __restrict__ rcnt) {
    __shared__ int lh[N_REL];
    for (int i = threadIdx.x; i < N_REL; i += 256) lh[i] = 0;
    __syncthreads();
    int e0 = blockIdx.x * 1024 + threadIdx.x * 4;
    #pragma unroll
    for (int k = 0; k < 4; ++k) {
        int e = e0 + k;
        if (e < NE) {
            atomicAdd(scnt + trip[3 * e], 1);
            atomicAdd(&lh[trip[3 * e + 2]], 1);
        }
    }
    __syncthreads();
    for (int i = threadIdx.x; i < N_REL; i += 256)
        if (lh[i]) atomicAdd(rcnt + i, lh[i]);
}

__global__ void k_scan1(const int* __restrict__ cnt, int* __restrict__ escan,
                        int* __restrict__ bsum) {
    __shared__ int sh[256];
    const int t = threadIdx.x;
    int base = blockIdx.x * 1024 + t * 4;
    int v[4]; int s = 0;
    #pragma unroll
    for (int k = 0; k < 4; ++k) { int idx = base + k; v[k] = (idx < N_ENT) ? cnt[idx] : 0; s += v[k]; }
    sh[t] = s; __syncthreads();
    for (int off = 1; off < 256; off <<= 1) {
        int u = (t >= off) ? sh[t - off] : 0;
        __syncthreads();
        sh[t] += u;
        __syncthreads();
    }
    int run = sh[t] - s;
    #pragma unroll
    for (int k = 0; k < 4; ++k) { int idx = base + k; if (idx < N_ENT) escan[idx] = run; run += v[k]; }
    if (t == 255) bsum[blockIdx.x] = sh[255];
}

__global__ void k_scan2(int* __restrict__ bsum) {
    __shared__ int sh[128];
    const int t = threadIdx.x;
    int v = (t < 98) ? bsum[t] : 0;
    sh[t] = v; __syncthreads();
    for (int off = 1; off < 128; off <<= 1) {
        int u = (t >= off) ? sh[t - off] : 0;
        __syncthreads();
        sh[t] += u;
        __syncthreads();
    }
    if (t < 98) bsum[t] = sh[t] - v;
}

__global__ void k_scan3(int* __restrict__ row_start, const int* __restrict__ bsum,
                        int* __restrict__ cursor) {
    int i = blockIdx.x * 256 + threadIdx.x;
    if (i < N_ENT) {
        int v = row_start[i] + bsum[i >> 10];
        row_start[i] = v;
        cursor[i] = v;
    } else if (i == N_ENT) {
        row_start[N_ENT] = NE;
    }
}

__global__ void k_relscan(const int* __restrict__ rcnt, int* __restrict__ rrow,
                          int* __restrict__ rcursor) {
    __shared__ int sh[256];
    const int t = threadIdx.x;
    int v = (t < N_REL) ? rcnt[t] : 0;
    sh[t] = v; __syncthreads();
    for (int off = 1; off < 256; off <<= 1) {
        int u = (t >= off) ? sh[t - off] : 0;
        __syncthreads();
        sh[t] += u;
        __syncthreads();
    }
    int excl = sh[t] - v;
    if (t <= N_REL) rrow[t] = excl;
    if (t < N_REL) rcursor[t] = excl;
}

// Scatter both CSRs; rel side block-aggregated (round-3 lesson). int2 payloads.
__global__ __launch_bounds__(256) void k_scatter3(const int* __restrict__ trip,
        int* __restrict__ scursor, int* __restrict__ rcursor,
        int2* __restrict__ sdr, int2* __restrict__ rsd) {
    __shared__ int lh[N_REL];
    __shared__ int lbase[N_REL];
    const int t = threadIdx.x;
    for (int i = t; i < N_REL; i += 256) lh[i] = 0;
    __syncthreads();

    const int e0 = blockIdx.x * 1024 + t * 4;
    int sv[4], dv[4], rv[4];
    #pragma unroll
    for (int k = 0; k < 4; ++k) {
        int e = e0 + k;
        if (e < NE) {
            sv[k] = trip[3 * e]; dv[k] = trip[3 * e + 1]; rv[k] = trip[3 * e + 2];
            atomicAdd(&lh[rv[k]], 1);
        } else { sv[k] = -1; }
    }
    __syncthreads();
    for (int i = t; i < N_REL; i += 256) {
        int c = lh[i];
        lbase[i] = c ? atomicAdd(rcursor + i, c) : 0;
        lh[i] = 0;
    }
    __syncthreads();
    #pragma unroll
    for (int k = 0; k < 4; ++k) {
        if (sv[k] >= 0) {
            int p1 = atomicAdd(scursor + sv[k], 1);
            sdr[p1] = make_int2(dv[k], rv[k]);
            int intra = atomicAdd(&lh[rv[k]], 1);
            rsd[lbase[rv[k]] + intra] = make_int2(sv[k], dv[k]);
        }
    }
}

// ---------------- FUSED edge kernel ----------------
// blockIdx < N_REL: rel path (one 16-wave block per rel, the long poles,
// dispatched first). Else: seg path, 16 entities per block (1 wave each).
__global__ __launch_bounds__(1024) void k_edges(const int* __restrict__ rrow,
        const int2* __restrict__ rsd,
        const int* __restrict__ row_start, const int2* __restrict__ sdr,
        const float* __restrict__ Ps, const float* __restrict__ Pd, const float* __restrict__ Pr,
        const float* __restrict__ qs, const float* __restrict__ qd, const float* __restrict__ qr,
        float* __restrict__ out) {
    __shared__ float red[16 * 128];
    __shared__ float reb[16];
    const int t = threadIdx.x;
    const int lane = t & 63;

    if (blockIdx.x < N_REL) {
        // ---- rel path ----
        const int r = blockIdx.x;
        const int w = t >> 6;
        const float myqr = qr[r];
        const int beg = rrow[r], end = rrow[r + 1];
        float a0 = 0.f, a1 = 0.f, ebs = 0.f;
        for (int j = beg + w; j < end; j += 16) {
            int2 sd = rsd[j];               // (src, dst) broadcast
            float b = myqr + qs[sd.x] + qd[sd.y];
            b = (b > 0.f) ? b : 0.01f * b;
            float eb = expf(b);
            a0 += eb * (Ps[(size_t)sd.x * DIM + lane]      + Pd[(size_t)sd.y * DIM + lane]);
            a1 += eb * (Ps[(size_t)sd.x * DIM + 64 + lane] + Pd[(size_t)sd.y * DIM + 64 + lane]);
            ebs += eb;
        }
        red[w * 128 + lane]      = a0;
        red[w * 128 + 64 + lane] = a1;
        if (lane == 0) reb[w] = ebs;   // per-WAVE scalar (round-5 lesson: no shfl!)
        __syncthreads();
        if (t < 128) {
            float ssum = 0.f, et = 0.f;
            #pragma unroll
            for (int ww = 0; ww < 16; ++ww) { ssum += red[ww * 128 + t]; et += reb[ww]; }
            float h = (ssum + et * Pr[r * DIM + t]) / fmaxf((float)(end - beg), 1.0f);
            out[(size_t)N_ENT * DIM + r * DIM + t] = (h > 0.f) ? h : expm1f(h);
        }
    } else {
        // ---- seg path: one wave per src entity ----
        const int s = (blockIdx.x - N_REL) * 16 + (t >> 6);
        if (s >= N_ENT) return;
        const int beg = row_start[s], end = row_start[s + 1];
        if (beg == end) {
            out[(size_t)s * DIM + lane] = 0.f;
            out[(size_t)s * DIM + 64 + lane] = 0.f;
            return;
        }
        const float myqs = qs[s];
        float acc0 = 0.f, acc1 = 0.f, ebs = 0.f;
        for (int j = beg; j < end; ++j) {
            int2 dr = sdr[j];               // (dst, rel) broadcast
            float b = myqs + qr[dr.y] + qd[dr.x];
            b = (b > 0.f) ? b : 0.01f * b;  // leaky_relu slope 0.01
            float eb = expf(b);
            acc0 += eb * (Pr[dr.y * DIM + lane]      + Pd[(size_t)dr.x * DIM + lane]);
            acc1 += eb * (Pr[dr.y * DIM + 64 + lane] + Pd[(size_t)dr.x * DIM + 64 + lane]);
            ebs += eb;
        }
        float h0 = Ps[(size_t)s * DIM + lane]      + acc0 / ebs;
        float h1 = Ps[(size_t)s * DIM + 64 + lane] + acc1 / ebs;
        out[(size_t)s * DIM + lane]      = (h0 > 0.f) ? h0 : expm1f(h0);  // elu
        out[(size_t)s * DIM + 64 + lane] = (h1 > 0.f) ? h1 : expm1f(h1);
    }
}

extern "C" void kernel_launch(void* const* d_in, const int* in_sizes, int n_in,
                              void* d_out, int out_size, void* d_ws, size_t ws_size,
                              hipStream_t stream) {
    const int*   trip = (const int*)d_in[0];
    const float* ent  = (const float*)d_in[1];
    const float* rele = (const float*)d_in[2];
    const float* Wa   = (const float*)d_in[3];
    const float* ba   = (const float*)d_in[4];
    const float* Wa2  = (const float*)d_in[5];
    const float* ba2  = (const float*)d_in[6];
    float* out = (float*)d_out;

    float* ws  = (float*)d_ws;
    float* Ps  = ws;                                    // N_ENT*128
    float* Pd  = Ps + (size_t)N_ENT * DIM;              // N_ENT*128
    float* Pr  = Pd + (size_t)N_ENT * DIM;              // N_REL*128
    float* qs  = Pr + N_REL * DIM;                      // N_ENT
    float* qd  = qs + N_ENT;                            // N_ENT
    float* qr  = qd + N_ENT;                            // 240
    float* vs  = qr + 240;                              // 128
    float* vd  = vs + 128;                              // 128
    unsigned short* Wah = (unsigned short*)(vd + 128);  // 128*384 bf16 (24576 floats)
    int* row_start = (int*)(vd + 128 + 24576);          // N_ENT+1
    int* cursor    = row_start + N_ENT + 1;             // N_ENT   \ one memset
    int* rcnt      = cursor + N_ENT;                    // 240     /
    int* rrow      = rcnt + 240;                        // 240
    int* rcursor   = rrow + 240;                        // 240
    int* bsum      = rcursor + 240;                     // 128
    int2* sdr      = (int2*)(bsum + 128);               // NE int2
    int2* rsd      = sdr + NE;                          // NE int2

    hipMemsetAsync(cursor, 0, (N_ENT + 240) * sizeof(int), stream);  // cursor + rcnt

    k_wah<<<192, 256, 0, stream>>>(Wa, Wah);
    k_vsd<<<1, 256, 0, stream>>>(Wa, Wa2, vs, vd);
    k_proj_rel<<<(N_REL * DIM + 255) / 256, 256, 0, stream>>>(rele, Wa, ba, Pr);
    k_qr<<<(N_REL * 64 + 255) / 256, 256, 0, stream>>>(Pr, Wa2, ba2, qr);
    k_proj_mfma<<<(N_ENT + 63) / 64, 256, 0, stream>>>(ent, Wah, vs, vd, Ps, Pd, qs, qd);

    k_hist2<<<(NE + 1023) / 1024, 256, 0, stream>>>(trip, cursor, rcnt);
    k_scan1<<<98, 256, 0, stream>>>(cursor, row_start, bsum);
    k_scan2<<<1, 128, 0, stream>>>(bsum);
    k_scan3<<<(N_ENT + 256) / 256, 256, 0, stream>>>(row_start, bsum, cursor);
    k_relscan<<<1, 256, 0, stream>>>(rcnt, rrow, rcursor);
    k_scatter3<<<(NE + 1023) / 1024, 256, 0, stream>>>(trip, cursor, rcursor, sdr, rsd);

    k_edges<<<N_REL + SEGB, 1024, 0, stream>>>(rrow, rsd, row_start, sdr,
                                               Ps, Pd, Pr, qs, qd, qr, out);
}

// Round 9
// 375.670 us; speedup vs baseline: 1.6993x; 1.0371x over previous
//
#include <hip/hip_runtime.h>
#include <math.h>

// Problem constants (from reference)
#define N_ENT 100000
#define N_REL 237
#define DIM   128
#define NE    400000
#define SEGB  ((N_ENT + 15) / 16)   // seg blocks in fused edge kernel (16 waves/blk)

typedef short bf16x8 __attribute__((ext_vector_type(8)));   // 8 bf16 in 4 VGPRs
typedef float f32x4  __attribute__((ext_vector_type(4)));

// ---------------------------------------------------------------------------
// Pipeline:
//  1. k_prep0: Wah = bf16(Wa); vs/vd = Wa_seg^T.w2 (exact fp32 logit vectors).
//     k_prep_rel: Pr row (fp32 + bf16 copy) + qr[r]=Pr.w2+ba2, one block/rel.
//  2. k_proj_mfma: Ps/Pd via bf16 MFMA 16x16x32, stored as BF16 tables
//     (halves gather + write bytes); qs/qd exact fp32 from same ent loads.
//  3. CSR build (block-aggregated rel reservation — round-3 lesson).
//  4. k_edges: fused seg+rel gather. Tables gathered as bf16 pairs:
//     lane owns dims (2*lane, 2*lane+1) -> one uint load/row/lane, decode =
//     2 bit-ops (bf16<<16 IS fp32). Round-7: fp32 gathers = 344MB FETCH,
//     138us; bf16 halves the bytes. e_b path stays exact fp32.
// (Round 8 never ran — GPU acquisition timeout; this is a clean resubmit.)
// ---------------------------------------------------------------------------

__device__ __forceinline__ unsigned short f2bf(float f) {
    unsigned int u = __float_as_uint(f);
    u += 0x7FFF + ((u >> 16) & 1);          // RNE
    return (unsigned short)(u >> 16);
}
__device__ __forceinline__ float bflo(unsigned int v) { return __uint_as_float(v << 16); }
__device__ __forceinline__ float bfhi(unsigned int v) { return __uint_as_float(v & 0xffff0000u); }

// blocks 0..191: Wah conversion; block 192: vs/vd (vs[k]=sum_j Wa[j][k]w2[j])
__global__ void k_prep0(const float* __restrict__ Wa, unsigned short* __restrict__ Wah,
                        const float* __restrict__ Wa2, float* __restrict__ vs,
                        float* __restrict__ vd) {
    if (blockIdx.x < 192) {
        int i = blockIdx.x * 256 + threadIdx.x;
        if (i < 128 * 384) Wah[i] = f2bf(Wa[i]);
    } else {
        int t = threadIdx.x;
        if (t < 128) {
            float a = 0.f;
            for (int j = 0; j < 128; ++j) a += Wa[j * 384 + t] * Wa2[j];
            vs[t] = a;
        } else {
            int k = t - 128;
            float a = 0.f;
            for (int j = 0; j < 128; ++j) a += Wa[j * 384 + 256 + k] * Wa2[j];
            vd[k] = a;
        }
    }
}

// one block (128 thr) per rel: Pr row fp32+bf16, then qr via LDS reduce
__global__ void k_prep_rel(const float* __restrict__ rel_e, const float* __restrict__ Wa,
                           const float* __restrict__ ba, const float* __restrict__ Wa2,
                           const float* __restrict__ ba2, float* __restrict__ Pr,
                           unsigned short* __restrict__ Prh, float* __restrict__ qr) {
    __shared__ float sred[128];
    const int r = blockIdx.x, j = threadIdx.x;
    float acc = ba[j];
    const float* wrow = Wa + j * 384 + 128;
    const float* erow = rel_e + r * DIM;
    #pragma unroll 8
    for (int k = 0; k < DIM; ++k) acc += erow[k] * wrow[k];
    Pr[r * DIM + j]  = acc;
    Prh[r * DIM + j] = f2bf(acc);
    sred[j] = acc * Wa2[j];
    __syncthreads();
    for (int off = 64; off > 0; off >>= 1) {
        if (j < off) sred[j] += sred[j + off];
        __syncthreads();
    }
    if (j == 0) qr[r] = sred[0] + ba2[0];
}

// bf16-MFMA projection -> BF16 tables. Per wave: 16 rows x 128 cols of both.
// C/D mapping: col=lane&15, row=(lane>>4)*4+reg (verified round 7).
__global__ __launch_bounds__(256) void k_proj_mfma(const float* __restrict__ ent,
        const unsigned short* __restrict__ Wah,
        const float* __restrict__ vs, const float* __restrict__ vd,
        unsigned short* __restrict__ Psh, unsigned short* __restrict__ Pdh,
        float* __restrict__ qs, float* __restrict__ qd) {
    const int wave = threadIdx.x >> 6, lane = threadIdx.x & 63;
    const int row0 = blockIdx.x * 64 + wave * 16;
    const int lr = lane & 15;
    const int lg = lane >> 4;
    const int arow = (row0 + lr < N_ENT) ? row0 + lr : (N_ENT - 1);

    f32x4 accS[8], accD[8];
    #pragma unroll
    for (int t = 0; t < 8; ++t) {
        accS[t] = (f32x4){0.f, 0.f, 0.f, 0.f};
        accD[t] = (f32x4){0.f, 0.f, 0.f, 0.f};
    }
    float qsp = 0.f, qdp = 0.f;

    #pragma unroll
    for (int kk = 0; kk < 4; ++kk) {
        const int k0 = kk * 32 + lg * 8;
        const float* ep = ent + (size_t)arow * DIM + k0;
        float4 e0 = *(const float4*)ep;
        float4 e1 = *(const float4*)(ep + 4);
        float4 v0 = *(const float4*)(vs + k0);
        float4 v1 = *(const float4*)(vs + k0 + 4);
        qsp += e0.x*v0.x + e0.y*v0.y + e0.z*v0.z + e0.w*v0.w
             + e1.x*v1.x + e1.y*v1.y + e1.z*v1.z + e1.w*v1.w;
        float4 u0 = *(const float4*)(vd + k0);
        float4 u1 = *(const float4*)(vd + k0 + 4);
        qdp += e0.x*u0.x + e0.y*u0.y + e0.z*u0.z + e0.w*u0.w
             + e1.x*u1.x + e1.y*u1.y + e1.z*u1.z + e1.w*u1.w;
        bf16x8 a;
        a[0] = (short)f2bf(e0.x); a[1] = (short)f2bf(e0.y);
        a[2] = (short)f2bf(e0.z); a[3] = (short)f2bf(e0.w);
        a[4] = (short)f2bf(e1.x); a[5] = (short)f2bf(e1.y);
        a[6] = (short)f2bf(e1.z); a[7] = (short)f2bf(e1.w);
        #pragma unroll
        for (int t = 0; t < 8; ++t) {
            const size_t wb = (size_t)(t * 16 + lr) * 384 + k0;
            bf16x8 bs = *(const bf16x8*)(Wah + wb);
            bf16x8 bd = *(const bf16x8*)(Wah + wb + 256);
            accS[t] = __builtin_amdgcn_mfma_f32_16x16x32_bf16(a, bs, accS[t], 0, 0, 0);
            accD[t] = __builtin_amdgcn_mfma_f32_16x16x32_bf16(a, bd, accD[t], 0, 0, 0);
        }
    }

    #pragma unroll
    for (int q = 0; q < 4; ++q) {
        const int row = row0 + lg * 4 + q;
        if (row < N_ENT) {
            #pragma unroll
            for (int t = 0; t < 8; ++t) {
                Psh[(size_t)row * DIM + t * 16 + lr] = f2bf(accS[t][q]);
                Pdh[(size_t)row * DIM + t * 16 + lr] = f2bf(accD[t][q]);
            }
        }
    }

    qsp += __shfl_xor(qsp, 16, 64); qsp += __shfl_xor(qsp, 32, 64);
    qdp += __shfl_xor(qdp, 16, 64); qdp += __shfl_xor(qdp, 32, 64);
    if (lane < 16 && row0 + lane < N_ENT) {
        qs[row0 + lane] = qsp;
        qd[row0 + lane] = qdp;
    }
}

// ---------------- CSR build ----------------
__global__ void k_hist2(const int* __restrict__ trip, int* __restrict__ scnt,
                        int* __restrict__ rcnt) {
    __shared__ int lh[N_REL];
    for (int i = threadIdx.x; i < N_REL; i += 256) lh[i] = 0;
    __syncthreads();
    int e0 = blockIdx.x * 1024 + threadIdx.x * 4;
    #pragma unroll
    for (int k = 0; k < 4; ++k) {
        int e = e0 + k;
        if (e < NE) {
            atomicAdd(scnt + trip[3 * e], 1);
            atomicAdd(&lh[trip[3 * e + 2]], 1);
        }
    }
    __syncthreads();
    for (int i = threadIdx.x; i < N_REL; i += 256)
        if (lh[i]) atomicAdd(rcnt + i, lh[i]);
}

__global__ void k_scan1(const int* __restrict__ cnt, int* __restrict__ escan,
                        int* __restrict__ bsum) {
    __shared__ int sh[256];
    const int t = threadIdx.x;
    int base = blockIdx.x * 1024 + t * 4;
    int v[4]; int s = 0;
    #pragma unroll
    for (int k = 0; k < 4; ++k) { int idx = base + k; v[k] = (idx < N_ENT) ? cnt[idx] : 0; s += v[k]; }
    sh[t] = s; __syncthreads();
    for (int off = 1; off < 256; off <<= 1) {
        int u = (t >= off) ? sh[t - off] : 0;
        __syncthreads();
        sh[t] += u;
        __syncthreads();
    }
    int run = sh[t] - s;
    #pragma unroll
    for (int k = 0; k < 4; ++k) { int idx = base + k; if (idx < N_ENT) escan[idx] = run; run += v[k]; }
    if (t == 255) bsum[blockIdx.x] = sh[255];
}

__global__ void k_scan2(int* __restrict__ bsum) {
    __shared__ int sh[128];
    const int t = threadIdx.x;
    int v = (t < 98) ? bsum[t] : 0;
    sh[t] = v; __syncthreads();
    for (int off = 1; off < 128; off <<= 1) {
        int u = (t >= off) ? sh[t - off] : 0;
        __syncthreads();
        sh[t] += u;
        __syncthreads();
    }
    if (t < 98) bsum[t] = sh[t] - v;
}

__global__ void k_scan3(int* __restrict__ row_start, const int* __restrict__ bsum,
                        int* __restrict__ cursor) {
    int i = blockIdx.x * 256 + threadIdx.x;
    if (i < N_ENT) {
        int v = row_start[i] + bsum[i >> 10];
        row_start[i] = v;
        cursor[i] = v;
    } else if (i == N_ENT) {
        row_start[N_ENT] = NE;
    }
}

__global__ void k_relscan(const int* __restrict__ rcnt, int* __restrict__ rrow,
                          int* __restrict__ rcursor) {
    __shared__ int sh[256];
    const int t = threadIdx.x;
    int v = (t < N_REL) ? rcnt[t] : 0;
    sh[t] = v; __syncthreads();
    for (int off = 1; off < 256; off <<= 1) {
        int u = (t >= off) ? sh[t - off] : 0;
        __syncthreads();
        sh[t] += u;
        __syncthreads();
    }
    int excl = sh[t] - v;
    if (t <= N_REL) rrow[t] = excl;
    if (t < N_REL) rcursor[t] = excl;
}

// Scatter both CSRs; rel side block-aggregated (round-3 lesson). int2 payloads.
__global__ __launch_bounds__(256) void k_scatter3(const int* __restrict__ trip,
        int* __restrict__ scursor, int* __restrict__ rcursor,
        int2* __restrict__ sdr, int2* __restrict__ rsd) {
    __shared__ int lh[N_REL];
    __shared__ int lbase[N_REL];
    const int t = threadIdx.x;
    for (int i = t; i < N_REL; i += 256) lh[i] = 0;
    __syncthreads();

    const int e0 = blockIdx.x * 1024 + t * 4;
    int sv[4], dv[4], rv[4];
    #pragma unroll
    for (int k = 0; k < 4; ++k) {
        int e = e0 + k;
        if (e < NE) {
            sv[k] = trip[3 * e]; dv[k] = trip[3 * e + 1]; rv[k] = trip[3 * e + 2];
            atomicAdd(&lh[rv[k]], 1);
        } else { sv[k] = -1; }
    }
    __syncthreads();
    for (int i = t; i < N_REL; i += 256) {
        int c = lh[i];
        lbase[i] = c ? atomicAdd(rcursor + i, c) : 0;
        lh[i] = 0;
    }
    __syncthreads();
    #pragma unroll
    for (int k = 0; k < 4; ++k) {
        if (sv[k] >= 0) {
            int p1 = atomicAdd(scursor + sv[k], 1);
            sdr[p1] = make_int2(dv[k], rv[k]);
            int intra = atomicAdd(&lh[rv[k]], 1);
            rsd[lbase[rv[k]] + intra] = make_int2(sv[k], dv[k]);
        }
    }
}

// ---------------- FUSED edge kernel (bf16 gathers) ----------------
// Lane owns dims (2*lane, 2*lane+1): one uint per table row per lane.
__global__ __launch_bounds__(1024) void k_edges(const int* __restrict__ rrow,
        const int2* __restrict__ rsd,
        const int* __restrict__ row_start, const int2* __restrict__ sdr,
        const unsigned short* __restrict__ Psh, const unsigned short* __restrict__ Pdh,
        const unsigned short* __restrict__ Prh, const float* __restrict__ Pr,
        const float* __restrict__ qs, const float* __restrict__ qd, const float* __restrict__ qr,
        float* __restrict__ out) {
    __shared__ float red[16 * 128];
    __shared__ float reb[16];
    const int t = threadIdx.x;
    const int lane = t & 63;
    const int dl = 2 * lane;            // this lane's dim pair base

    if (blockIdx.x < N_REL) {
        // ---- rel path ----
        const int r = blockIdx.x;
        const int w = t >> 6;
        const float myqr = qr[r];
        const int beg = rrow[r], end = rrow[r + 1];
        float a0 = 0.f, a1 = 0.f, ebs = 0.f;
        for (int j = beg + w; j < end; j += 16) {
            int2 sd = rsd[j];
            float b = myqr + qs[sd.x] + qd[sd.y];
            b = (b > 0.f) ? b : 0.01f * b;
            float eb = expf(b);
            unsigned int ps = *(const unsigned int*)(Psh + (size_t)sd.x * DIM + dl);
            unsigned int pd = *(const unsigned int*)(Pdh + (size_t)sd.y * DIM + dl);
            a0 += eb * (bflo(ps) + bflo(pd));
            a1 += eb * (bfhi(ps) + bfhi(pd));
            ebs += eb;
        }
        *(float2*)(red + w * 128 + dl) = make_float2(a0, a1);
        if (lane == 0) reb[w] = ebs;    // per-WAVE scalar (round-5 lesson: no shfl!)
        __syncthreads();
        if (t < 128) {
            float ssum = 0.f, et = 0.f;
            #pragma unroll
            for (int ww = 0; ww < 16; ++ww) { ssum += red[ww * 128 + t]; et += reb[ww]; }
            float h = (ssum + et * Pr[r * DIM + t]) / fmaxf((float)(end - beg), 1.0f);
            out[(size_t)N_ENT * DIM + r * DIM + t] = (h > 0.f) ? h : expm1f(h);
        }
    } else {
        // ---- seg path: one wave per src entity ----
        const int s = (blockIdx.x - N_REL) * 16 + (t >> 6);
        if (s >= N_ENT) return;
        const int beg = row_start[s], end = row_start[s + 1];
        if (beg == end) {
            *(float2*)(out + (size_t)s * DIM + dl) = make_float2(0.f, 0.f);
            return;
        }
        const float myqs = qs[s];
        float acc0 = 0.f, acc1 = 0.f, ebs = 0.f;
        for (int j = beg; j < end; ++j) {
            int2 dr = sdr[j];
            float b = myqs + qr[dr.y] + qd[dr.x];
            b = (b > 0.f) ? b : 0.01f * b;  // leaky_relu slope 0.01
            float eb = expf(b);
            unsigned int pr = *(const unsigned int*)(Prh + (size_t)dr.y * DIM + dl);
            unsigned int pd = *(const unsigned int*)(Pdh + (size_t)dr.x * DIM + dl);
            acc0 += eb * (bflo(pr) + bflo(pd));
            acc1 += eb * (bfhi(pr) + bfhi(pd));
            ebs += eb;
        }
        unsigned int ps = *(const unsigned int*)(Psh + (size_t)s * DIM + dl);
        float h0 = bflo(ps) + acc0 / ebs;
        float h1 = bfhi(ps) + acc1 / ebs;
        h0 = (h0 > 0.f) ? h0 : expm1f(h0);  // elu
        h1 = (h1 > 0.f) ? h1 : expm1f(h1);
        *(float2*)(out + (size_t)s * DIM + dl) = make_float2(h0, h1);
    }
}

extern "C" void kernel_launch(void* const* d_in, const int* in_sizes, int n_in,
                              void* d_out, int out_size, void* d_ws, size_t ws_size,
                              hipStream_t stream) {
    const int*   trip = (const int*)d_in[0];
    const float* ent  = (const float*)d_in[1];
    const float* rele = (const float*)d_in[2];
    const float* Wa   = (const float*)d_in[3];
    const float* ba   = (const float*)d_in[4];
    const float* Wa2  = (const float*)d_in[5];
    const float* ba2  = (const float*)d_in[6];
    float* out = (float*)d_out;

    float* ws  = (float*)d_ws;
    float* Pr  = ws;                                    // N_REL*128 fp32
    float* qs  = Pr + N_REL * DIM;                      // N_ENT
    float* qd  = qs + N_ENT;                            // N_ENT
    float* qr  = qd + N_ENT;                            // 240
    float* vs  = qr + 240;                              // 128
    float* vd  = vs + 128;                              // 128
    unsigned short* Psh = (unsigned short*)(vd + 128);  // N_ENT*128 bf16
    unsigned short* Pdh = Psh + (size_t)N_ENT * DIM;    // N_ENT*128 bf16
    unsigned short* Prh = Pdh + (size_t)N_ENT * DIM;    // N_REL*128 bf16
    unsigned short* Wah = Prh + N_REL * DIM;            // 128*384 bf16
    int* row_start = (int*)(Wah + 128 * 384);           // N_ENT+1
    int* cursor    = row_start + N_ENT + 1;             // N_ENT   \ one memset
    int* rcnt      = cursor + N_ENT;                    // 240     /
    int* rrow      = rcnt + 240;                        // 240
    int* rcursor   = rrow + 240;                        // 240
    int* bsum      = rcursor + 240;                     // 128
    int2* sdr      = (int2*)(bsum + 128);               // NE int2
    int2* rsd      = sdr + NE;                          // NE int2

    hipMemsetAsync(cursor, 0, (N_ENT + 240) * sizeof(int), stream);  // cursor + rcnt

    k_prep0<<<193, 256, 0, stream>>>(Wa, Wah, Wa2, vs, vd);
    k_prep_rel<<<N_REL, 128, 0, stream>>>(rele, Wa, ba, Wa2, ba2, Pr, Prh, qr);
    k_proj_mfma<<<(N_ENT + 63) / 64, 256, 0, stream>>>(ent, Wah, vs, vd,
                                                       Psh, Pdh, qs, qd);

    k_hist2<<<(NE + 1023) / 1024, 256, 0, stream>>>(trip, cursor, rcnt);
    k_scan1<<<98, 256, 0, stream>>>(cursor, row_start, bsum);
    k_scan2<<<1, 128, 0, stream>>>(bsum);
    k_scan3<<<(N_ENT + 256) / 256, 256, 0, stream>>>(row_start, bsum, cursor);
    k_relscan<<<1, 256, 0, stream>>>(rcnt, rrow, rcursor);
    k_scatter3<<<(NE + 1023) / 1024, 256, 0, stream>>>(trip, cursor, rcursor, sdr, rsd);

    k_edges<<<N_REL + SEGB, 1024, 0, stream>>>(rrow, rsd, row_start, sdr,
                                               Psh, Pdh, Prh, Pr, qs, qd, qr, out);
}